// Round 1
// baseline (256.223 us; speedup 1.0000x reference)
//
#include <hip/hip_runtime.h>
#include <hip/hip_bf16.h>

// Shapes (fixed for this problem)
#define BB 2
#define NN 16
#define CC 256
#define KK 64
#define HW 4096
#define NH 8

// ---------------------------------------------------------------------------
// K1: key_n = softmax(key_map, axis=K). One thread per (b,hw); 64 values in regs.
// ---------------------------------------------------------------------------
__global__ __launch_bounds__(64) void k_softmax(const float* __restrict__ km,
                                                float* __restrict__ keyn) {
    const int b = blockIdx.x >> 6;                 // HW/64 = 64 blocks per b
    const int hw = (blockIdx.x & 63) * 64 + threadIdx.x;
    const float* p = km + (size_t)b * KK * HW + hw;
    float x[KK];
    float m = -1e30f;
#pragma unroll
    for (int k = 0; k < KK; k++) { x[k] = p[(size_t)k * HW]; m = fmaxf(m, x[k]); }
    float s = 0.f;
#pragma unroll
    for (int k = 0; k < KK; k++) { x[k] = __expf(x[k] - m); s += x[k]; }
    const float inv = 1.f / s;
    float* q = keyn + (size_t)b * KK * HW + hw;
#pragma unroll
    for (int k = 0; k < KK; k++) q[(size_t)k * HW] = x[k] * inv;
}

// ---------------------------------------------------------------------------
// K2: gram[b,k,j] = sum_hw key_n[b,k,hw]*key_n[b,j,hw]. Block per (b,k,j).
// ---------------------------------------------------------------------------
__global__ __launch_bounds__(256) void k_gram(const float* __restrict__ keyn,
                                              float* __restrict__ gram) {
    const int tid = threadIdx.x;
    const int id = blockIdx.x;
    const int b = id >> 12;
    const int k = (id >> 6) & 63;
    const int j = id & 63;
    const float* pa = keyn + ((size_t)b * KK + k) * HW;
    const float* pb = keyn + ((size_t)b * KK + j) * HW;
    float s = 0.f;
    for (int i = tid; i < HW; i += 256) s = fmaf(pa[i], pb[i], s);
#pragma unroll
    for (int off = 32; off; off >>= 1) s += __shfl_down(s, off, 64);
    __shared__ float red[4];
    if ((tid & 63) == 0) red[tid >> 6] = s;
    __syncthreads();
    if (tid == 0) gram[id] = red[0] + red[1] + red[2] + red[3];
}

// ---------------------------------------------------------------------------
// K3: per (b,n,k): beta_h, alpha_h (dot over c), v_k (gram @ state),
//     part = alpha*(state - beta*v_k). Block per (b,n,k), thread = c.
// ---------------------------------------------------------------------------
__global__ __launch_bounds__(256) void k_state(const float* __restrict__ state,
                                               const float* __restrict__ gram,
                                               const float* __restrict__ b_w,
                                               const float* __restrict__ a_w,
                                               const float* __restrict__ A_log,
                                               const float* __restrict__ dt_bias,
                                               float* __restrict__ part,
                                               float* __restrict__ beta8) {
    const int tid = threadIdx.x;   // c
    const int id = blockIdx.x;     // (b*N+n)*K + k
    const int k = id & 63;
    const int bn = id >> 6;
    const int b = bn >> 4;
    const float* st = state + (size_t)bn * KK * CC;   // [j][c]
    const float s = st[(size_t)k * CC + tid];

    float pb[NH], pa[NH];
#pragma unroll
    for (int h = 0; h < NH; h++) {
        pb[h] = s * b_w[h * CC + tid];
        pa[h] = s * a_w[h * CC + tid];
    }
#pragma unroll
    for (int off = 32; off; off >>= 1) {
#pragma unroll
        for (int h = 0; h < NH; h++) {
            pb[h] += __shfl_down(pb[h], off, 64);
            pa[h] += __shfl_down(pa[h], off, 64);
        }
    }
    __shared__ float red[4][2 * NH];
    const int wave = tid >> 6, lane = tid & 63;
    if (lane == 0) {
#pragma unroll
        for (int h = 0; h < NH; h++) { red[wave][h] = pb[h]; red[wave][NH + h] = pa[h]; }
    }
    __syncthreads();
    const int h = tid >> 5;   // c / 32 (rep = 32)
    float braw = 0.f, araw = 0.f;
#pragma unroll
    for (int w = 0; w < 4; w++) { braw += red[w][h]; araw += red[w][NH + h]; }
    const float beta = 1.f / (1.f + __expf(-braw));
    const float xx = araw + dt_bias[h];
    const float sp = fmaxf(xx, 0.f) + log1pf(__expf(-fabsf(xx)));   // softplus
    const float alpha = -__expf(A_log[h]) * sp;

    const float* g = gram + ((size_t)b * KK + k) * KK;
    float vk = 0.f;
#pragma unroll
    for (int j = 0; j < KK; j++) vk = fmaf(g[j], st[(size_t)j * CC + tid], vk);

    part[(size_t)id * CC + tid] = alpha * (s - beta * vk);
    if ((tid & 31) == 0) beta8[(size_t)id * NH + h] = beta;
}

// ---------------------------------------------------------------------------
// K4: vk_t[b,n,k,c] = sum_hw key_n[b,k,hw] * value[b,n,c,hw]   (inner = 4096)
//     then new_state = part + beta * vk_t.
// Block per (b,n, 32-wide c tile): 256 blocks, 256 threads.
// Output tile 64(k) x 32(c); thread tile 4x2; LDS-staged, SW-pipelined loads.
// ---------------------------------------------------------------------------
__global__ __launch_bounds__(256) void k_vkt(const float* __restrict__ keyn,
                                             const float* __restrict__ value,
                                             const float* __restrict__ part,
                                             const float* __restrict__ beta8,
                                             float* __restrict__ ns) {
    const int tid = threadIdx.x;
    const int id = blockIdx.x;
    const int cb = id & 7;
    const int bn = id >> 3;
    const int b = bn >> 4;
    const int c0 = cb * 32;
    const float* kn = keyn + (size_t)b * KK * HW;
    const float* val = value + ((size_t)bn * CC + c0) * HW;

    __shared__ __align__(16) float As[32][68];   // [hw][k]   (pad 68: aligned + ~2-way reads)
    __shared__ __align__(16) float Bs[32][34];   // [hw][c]

    const int ty = tid >> 4, tx = tid & 15;      // ty: k-quad, tx: c-pair
    float acc[4][2] = {{0.f,0.f},{0.f,0.f},{0.f,0.f},{0.f,0.f}};

    float ra[8], rb[4];
#pragma unroll
    for (int i = 0; i < 8; i++) {
        int idx = i * 256 + tid;
        ra[i] = kn[(size_t)(idx >> 5) * HW + (idx & 31)];
    }
#pragma unroll
    for (int i = 0; i < 4; i++) {
        int idx = i * 256 + tid;
        rb[i] = val[(size_t)(idx >> 5) * HW + (idx & 31)];
    }

    for (int hw0 = 0; hw0 < HW; hw0 += 32) {
        __syncthreads();   // previous compute done before LDS overwrite
#pragma unroll
        for (int i = 0; i < 8; i++) { int idx = i * 256 + tid; As[idx & 31][idx >> 5] = ra[i]; }
#pragma unroll
        for (int i = 0; i < 4; i++) { int idx = i * 256 + tid; Bs[idx & 31][idx >> 5] = rb[i]; }
        __syncthreads();
        if (hw0 + 32 < HW) {     // prefetch next chunk into regs (hides HBM latency)
#pragma unroll
            for (int i = 0; i < 8; i++) {
                int idx = i * 256 + tid;
                ra[i] = kn[(size_t)(idx >> 5) * HW + hw0 + 32 + (idx & 31)];
            }
#pragma unroll
            for (int i = 0; i < 4; i++) {
                int idx = i * 256 + tid;
                rb[i] = val[(size_t)(idx >> 5) * HW + hw0 + 32 + (idx & 31)];
            }
        }
#pragma unroll
        for (int hw = 0; hw < 32; hw++) {
            const float4 a = *(const float4*)&As[hw][ty * 4];
            const float2 bv = *(const float2*)&Bs[hw][tx * 2];
            acc[0][0] = fmaf(a.x, bv.x, acc[0][0]); acc[0][1] = fmaf(a.x, bv.y, acc[0][1]);
            acc[1][0] = fmaf(a.y, bv.x, acc[1][0]); acc[1][1] = fmaf(a.y, bv.y, acc[1][1]);
            acc[2][0] = fmaf(a.z, bv.x, acc[2][0]); acc[2][1] = fmaf(a.z, bv.y, acc[2][1]);
            acc[3][0] = fmaf(a.w, bv.x, acc[3][0]); acc[3][1] = fmaf(a.w, bv.y, acc[3][1]);
        }
    }

    __shared__ float betaL[KK];
    __syncthreads();
    if (tid < KK) betaL[tid] = beta8[(size_t)(bn * KK + tid) * NH + cb];
    __syncthreads();
#pragma unroll
    for (int i = 0; i < 4; i++) {
        const int k = ty * 4 + i;
        const float bet = betaL[k];
        const size_t base = ((size_t)bn * KK + k) * CC + c0 + tx * 2;
        ns[base]     = part[base]     + bet * acc[i][0];
        ns[base + 1] = part[base + 1] + bet * acc[i][1];
    }
}

// ---------------------------------------------------------------------------
// K5: readout[b,n,c,hw] = sum_k key_n[b,k,hw] * ns[b,n,k,c]   (inner = 64)
// Block per (b,n, 16-c tile, 256-hw tile): 8192 blocks. ns tile in LDS
// (broadcast float4 reads), key_n from L2, coalesced output writes.
// ---------------------------------------------------------------------------
__global__ __launch_bounds__(256) void k_readout(const float* __restrict__ keyn,
                                                 const float* __restrict__ ns,
                                                 float* __restrict__ out) {
    const int tid = threadIdx.x;
    const int id = blockIdx.x;        // ((bn)*16 + ct)*16 + hwt
    const int hwt = id & 15;
    const int ct = (id >> 4) & 15;
    const int bn = id >> 8;
    const int b = bn >> 4;

    __shared__ __align__(16) float nsL[KK][20];   // 16 c + pad to keep float4 aligned
#pragma unroll
    for (int i = 0; i < 4; i++) {
        int idx = i * 256 + tid;
        int k = idx >> 4, c = idx & 15;
        nsL[k][c] = ns[((size_t)bn * KK + k) * CC + ct * 16 + c];
    }
    __syncthreads();

    const int hw = hwt * 256 + tid;
    const float* kn = keyn + (size_t)b * KK * HW + hw;
    float acc[16];
#pragma unroll
    for (int c = 0; c < 16; c++) acc[c] = 0.f;
#pragma unroll 8
    for (int k = 0; k < KK; k++) {
        const float kv = kn[(size_t)k * HW];
        const float4* r = (const float4*)&nsL[k][0];
        const float4 n0 = r[0], n1 = r[1], n2 = r[2], n3 = r[3];
        acc[0]  = fmaf(kv, n0.x, acc[0]);  acc[1]  = fmaf(kv, n0.y, acc[1]);
        acc[2]  = fmaf(kv, n0.z, acc[2]);  acc[3]  = fmaf(kv, n0.w, acc[3]);
        acc[4]  = fmaf(kv, n1.x, acc[4]);  acc[5]  = fmaf(kv, n1.y, acc[5]);
        acc[6]  = fmaf(kv, n1.z, acc[6]);  acc[7]  = fmaf(kv, n1.w, acc[7]);
        acc[8]  = fmaf(kv, n2.x, acc[8]);  acc[9]  = fmaf(kv, n2.y, acc[9]);
        acc[10] = fmaf(kv, n2.z, acc[10]); acc[11] = fmaf(kv, n2.w, acc[11]);
        acc[12] = fmaf(kv, n3.x, acc[12]); acc[13] = fmaf(kv, n3.y, acc[13]);
        acc[14] = fmaf(kv, n3.z, acc[14]); acc[15] = fmaf(kv, n3.w, acc[15]);
    }
    float* o = out + ((size_t)bn * CC + ct * 16) * HW + hw;
#pragma unroll
    for (int c = 0; c < 16; c++) o[(size_t)c * HW] = acc[c];
}

// ---------------------------------------------------------------------------
extern "C" void kernel_launch(void* const* d_in, const int* in_sizes, int n_in,
                              void* d_out, int out_size, void* d_ws, size_t ws_size,
                              hipStream_t stream) {
    const float* value   = (const float*)d_in[0];
    const float* key_map = (const float*)d_in[1];
    const float* state   = (const float*)d_in[2];
    const float* b_w     = (const float*)d_in[3];
    const float* a_w     = (const float*)d_in[4];
    const float* A_log   = (const float*)d_in[5];
    const float* dt_bias = (const float*)d_in[6];
    float* out = (float*)d_out;

    float* ws = (float*)d_ws;
    float* keyn  = ws;                     // B*K*HW      = 524288 floats
    float* gram  = keyn  + 524288;         // B*K*K       =   8192
    float* part  = gram  + 8192;           // B*N*K*C     = 524288
    float* beta8 = part  + 524288;         // B*N*K*NH    =  16384
    float* nstat = beta8 + 16384;          // B*N*K*C     = 524288
    // total ~6.4 MB of d_ws

    k_softmax<<<BB * (HW / 64), 64, 0, stream>>>(key_map, keyn);
    k_gram<<<BB * KK * KK, 256, 0, stream>>>(keyn, gram);
    k_state<<<BB * NN * KK, 256, 0, stream>>>(state, gram, b_w, a_w, A_log, dt_bias,
                                              part, beta8);
    k_vkt<<<BB * NN * (CC / 32), 256, 0, stream>>>(keyn, value, part, beta8, nstat);
    k_readout<<<BB * NN * (CC / 16) * (HW / 256), 256, 0, stream>>>(keyn, nstat, out);
}

// Round 2
// 158.430 us; speedup vs baseline: 1.6173x; 1.6173x over previous
//
#include <hip/hip_runtime.h>
#include <hip/hip_bf16.h>

// Shapes (fixed for this problem)
#define BB 2
#define NN 16
#define CC 256
#define KK 64
#define HW 4096
#define NH 8

typedef __attribute__((ext_vector_type(4))) float f32x4;
typedef __attribute__((ext_vector_type(8))) short s16x8;

__device__ __forceinline__ short f2bf(float f) {
    __hip_bfloat16 h = __float2bfloat16(f);
    return *reinterpret_cast<short*>(&h);
}

// ---------------------------------------------------------------------------
// K1: key_n = softmax(key_map, axis=K). One thread per (b,hw); 64 values in regs.
// Also emits a bf16 copy of key_n for the MFMA kernel.
// ---------------------------------------------------------------------------
__global__ __launch_bounds__(64) void k_softmax(const float* __restrict__ km,
                                                float* __restrict__ keyn,
                                                short* __restrict__ kbf) {
    const int b = blockIdx.x >> 6;                 // HW/64 = 64 blocks per b
    const int hw = (blockIdx.x & 63) * 64 + threadIdx.x;
    const float* p = km + (size_t)b * KK * HW + hw;
    float x[KK];
    float m = -1e30f;
#pragma unroll
    for (int k = 0; k < KK; k++) { x[k] = p[(size_t)k * HW]; m = fmaxf(m, x[k]); }
    float s = 0.f;
#pragma unroll
    for (int k = 0; k < KK; k++) { x[k] = __expf(x[k] - m); s += x[k]; }
    const float inv = 1.f / s;
    float* q = keyn + (size_t)b * KK * HW + hw;
    short* q2 = kbf + (size_t)b * KK * HW + hw;
#pragma unroll
    for (int k = 0; k < KK; k++) {
        const float y = x[k] * inv;
        q[(size_t)k * HW] = y;
        q2[(size_t)k * HW] = f2bf(y);
    }
}

// ---------------------------------------------------------------------------
// K2: gram[b,k,j] = sum_hw key_n[b,k,hw]*key_n[b,j,hw]. Block per (b,k,j).
// ---------------------------------------------------------------------------
__global__ __launch_bounds__(256) void k_gram(const float* __restrict__ keyn,
                                              float* __restrict__ gram) {
    const int tid = threadIdx.x;
    const int id = blockIdx.x;
    const int b = id >> 12;
    const int k = (id >> 6) & 63;
    const int j = id & 63;
    const float* pa = keyn + ((size_t)b * KK + k) * HW;
    const float* pb = keyn + ((size_t)b * KK + j) * HW;
    float s = 0.f;
    for (int i = tid; i < HW; i += 256) s = fmaf(pa[i], pb[i], s);
#pragma unroll
    for (int off = 32; off; off >>= 1) s += __shfl_down(s, off, 64);
    __shared__ float red[4];
    if ((tid & 63) == 0) red[tid >> 6] = s;
    __syncthreads();
    if (tid == 0) gram[id] = red[0] + red[1] + red[2] + red[3];
}

// ---------------------------------------------------------------------------
// K3: per (b,n,k): beta_h, alpha_h (dot over c), v_k (gram @ state),
//     part = alpha*(state - beta*v_k). Block per (b,n,k), thread = c.
// ---------------------------------------------------------------------------
__global__ __launch_bounds__(256) void k_state(const float* __restrict__ state,
                                               const float* __restrict__ gram,
                                               const float* __restrict__ b_w,
                                               const float* __restrict__ a_w,
                                               const float* __restrict__ A_log,
                                               const float* __restrict__ dt_bias,
                                               float* __restrict__ part,
                                               float* __restrict__ beta8) {
    const int tid = threadIdx.x;   // c
    const int id = blockIdx.x;     // (b*N+n)*K + k
    const int k = id & 63;
    const int bn = id >> 6;
    const int b = bn >> 4;
    const float* st = state + (size_t)bn * KK * CC;   // [j][c]
    const float s = st[(size_t)k * CC + tid];

    float pb[NH], pa[NH];
#pragma unroll
    for (int h = 0; h < NH; h++) {
        pb[h] = s * b_w[h * CC + tid];
        pa[h] = s * a_w[h * CC + tid];
    }
#pragma unroll
    for (int off = 32; off; off >>= 1) {
#pragma unroll
        for (int h = 0; h < NH; h++) {
            pb[h] += __shfl_down(pb[h], off, 64);
            pa[h] += __shfl_down(pa[h], off, 64);
        }
    }
    __shared__ float red[4][2 * NH];
    const int wave = tid >> 6, lane = tid & 63;
    if (lane == 0) {
#pragma unroll
        for (int h = 0; h < NH; h++) { red[wave][h] = pb[h]; red[wave][NH + h] = pa[h]; }
    }
    __syncthreads();
    const int h = tid >> 5;   // c / 32 (rep = 32)
    float braw = 0.f, araw = 0.f;
#pragma unroll
    for (int w = 0; w < 4; w++) { braw += red[w][h]; araw += red[w][NH + h]; }
    const float beta = 1.f / (1.f + __expf(-braw));
    const float xx = araw + dt_bias[h];
    const float sp = fmaxf(xx, 0.f) + log1pf(__expf(-fabsf(xx)));   // softplus
    const float alpha = -__expf(A_log[h]) * sp;

    const float* g = gram + ((size_t)b * KK + k) * KK;
    float vk = 0.f;
#pragma unroll
    for (int j = 0; j < KK; j++) vk = fmaf(g[j], st[(size_t)j * CC + tid], vk);

    part[(size_t)id * CC + tid] = alpha * (s - beta * vk);
    if ((tid & 31) == 0) beta8[(size_t)id * NH + h] = beta;
}

// ---------------------------------------------------------------------------
// K4 (MFMA): vk_t[b,n,k,c] = sum_hw key_n[b,k,hw] * value[b,n,c,hw]
//            ns = part + beta * vk_t
// Block per (b,n, 32-c tile): 256 blocks, 256 threads (4 waves).
// Wave w handles hw in [w*1024, w*1024+1024) (K-split); fragments are loaded
// straight from global (both operands K-contiguous), value cvt f32->bf16 in
// regs. 2-stage register prefetch. Cross-wave reduce + combine via LDS.
// ---------------------------------------------------------------------------
__global__ __launch_bounds__(256) void k_vkt_mfma(const short* __restrict__ kbf,
                                                  const float* __restrict__ value,
                                                  const float* __restrict__ part,
                                                  const float* __restrict__ beta8,
                                                  float* __restrict__ ns) {
    const int tid = threadIdx.x;
    const int id = blockIdx.x;        // bn*8 + ct
    const int ct = id & 7;
    const int bn = id >> 3;
    const int b  = bn >> 4;
    const int w = tid >> 6, lane = tid & 63;
    const int l15 = lane & 15;
    const int ko  = (lane >> 4) << 3;     // K offset within fragment: 0,8,16,24

    const short* Ap = kbf + (size_t)b * KK * HW + ko;                       // A: keyn[k][hw]
    const float* Vp = value + ((size_t)bn * CC + ct * 32) * HW + ko;        // B: value[c][hw]

    f32x4 acc[4][2];
#pragma unroll
    for (int m = 0; m < 4; m++)
#pragma unroll
        for (int n = 0; n < 2; n++) acc[m][n] = (f32x4){0.f, 0.f, 0.f, 0.f};

    const int hwbase = w * 1024;

    s16x8 a_cur[4];
    f32x4 v_cur[2][2];
#pragma unroll
    for (int m = 0; m < 4; m++)
        a_cur[m] = *(const s16x8*)(Ap + (size_t)(m * 16 + l15) * HW + hwbase);
#pragma unroll
    for (int n = 0; n < 2; n++) {
        const float* p = Vp + (size_t)(n * 16 + l15) * HW + hwbase;
        v_cur[n][0] = *(const f32x4*)p;
        v_cur[n][1] = *(const f32x4*)(p + 4);
    }

    for (int t = 0; t < 32; ++t) {
        s16x8 a_nxt[4];
        f32x4 v_nxt[2][2];
        if (t < 31) {                      // prefetch next K-chunk into regs
            const int h2 = hwbase + (t + 1) * 32;
#pragma unroll
            for (int m = 0; m < 4; m++)
                a_nxt[m] = *(const s16x8*)(Ap + (size_t)(m * 16 + l15) * HW + h2);
#pragma unroll
            for (int n = 0; n < 2; n++) {
                const float* p = Vp + (size_t)(n * 16 + l15) * HW + h2;
                v_nxt[n][0] = *(const f32x4*)p;
                v_nxt[n][1] = *(const f32x4*)(p + 4);
            }
        }
        s16x8 bf[2];
#pragma unroll
        for (int n = 0; n < 2; n++)
#pragma unroll
            for (int j = 0; j < 4; j++) {
                bf[n][j]     = f2bf(v_cur[n][0][j]);
                bf[n][4 + j] = f2bf(v_cur[n][1][j]);
            }
#pragma unroll
        for (int m = 0; m < 4; m++)
#pragma unroll
            for (int n = 0; n < 2; n++)
                acc[m][n] = __builtin_amdgcn_mfma_f32_16x16x32_bf16(a_cur[m], bf[n],
                                                                    acc[m][n], 0, 0, 0);
#pragma unroll
        for (int m = 0; m < 4; m++) a_cur[m] = a_nxt[m];
#pragma unroll
        for (int n = 0; n < 2; n++) { v_cur[n][0] = v_nxt[n][0]; v_cur[n][1] = v_nxt[n][1]; }
    }

    // cross-wave reduce (4 hw-quarters) + fused combine: ns = part + beta*vkt
    __shared__ float red[4][KK][33];
#pragma unroll
    for (int m = 0; m < 4; m++)
#pragma unroll
        for (int n = 0; n < 2; n++)
#pragma unroll
            for (int r = 0; r < 4; r++)
                red[w][m * 16 + (lane >> 4) * 4 + r][n * 16 + l15] = acc[m][n][r];
    __syncthreads();

    const int k  = tid >> 2;
    const int c8 = (tid & 3) * 8;
    const float bet = beta8[(size_t)(bn * KK + k) * NH + ct];   // head = c/32 = ct
    const size_t obase = ((size_t)bn * KK + k) * CC + ct * 32 + c8;
#pragma unroll
    for (int j = 0; j < 8; j++) {
        const int cl = c8 + j;
        const float s = red[0][k][cl] + red[1][k][cl] + red[2][k][cl] + red[3][k][cl];
        ns[obase + j] = part[obase + j] + bet * s;
    }
}

// ---------------------------------------------------------------------------
// K5: readout[b,n,c,hw] = sum_k key_n[b,k,hw] * ns[b,n,k,c]   (inner = 64)
// ---------------------------------------------------------------------------
__global__ __launch_bounds__(256) void k_readout(const float* __restrict__ keyn,
                                                 const float* __restrict__ ns,
                                                 float* __restrict__ out) {
    const int tid = threadIdx.x;
    const int id = blockIdx.x;        // ((bn)*16 + ct)*16 + hwt
    const int hwt = id & 15;
    const int ct = (id >> 4) & 15;
    const int bn = id >> 8;
    const int b = bn >> 4;

    __shared__ __align__(16) float nsL[KK][20];   // 16 c + pad
#pragma unroll
    for (int i = 0; i < 4; i++) {
        int idx = i * 256 + tid;
        int k = idx >> 4, c = idx & 15;
        nsL[k][c] = ns[((size_t)bn * KK + k) * CC + ct * 16 + c];
    }
    __syncthreads();

    const int hw = hwt * 256 + tid;
    const float* kn = keyn + (size_t)b * KK * HW + hw;
    float acc[16];
#pragma unroll
    for (int c = 0; c < 16; c++) acc[c] = 0.f;
#pragma unroll 8
    for (int k = 0; k < KK; k++) {
        const float kv = kn[(size_t)k * HW];
        const float4* r = (const float4*)&nsL[k][0];
        const float4 n0 = r[0], n1 = r[1], n2 = r[2], n3 = r[3];
        acc[0]  = fmaf(kv, n0.x, acc[0]);  acc[1]  = fmaf(kv, n0.y, acc[1]);
        acc[2]  = fmaf(kv, n0.z, acc[2]);  acc[3]  = fmaf(kv, n0.w, acc[3]);
        acc[4]  = fmaf(kv, n1.x, acc[4]);  acc[5]  = fmaf(kv, n1.y, acc[5]);
        acc[6]  = fmaf(kv, n1.z, acc[6]);  acc[7]  = fmaf(kv, n1.w, acc[7]);
        acc[8]  = fmaf(kv, n2.x, acc[8]);  acc[9]  = fmaf(kv, n2.y, acc[9]);
        acc[10] = fmaf(kv, n2.z, acc[10]); acc[11] = fmaf(kv, n2.w, acc[11]);
        acc[12] = fmaf(kv, n3.x, acc[12]); acc[13] = fmaf(kv, n3.y, acc[13]);
        acc[14] = fmaf(kv, n3.z, acc[14]); acc[15] = fmaf(kv, n3.w, acc[15]);
    }
    float* o = out + ((size_t)bn * CC + ct * 16) * HW + hw;
#pragma unroll
    for (int c = 0; c < 16; c++) o[(size_t)c * HW] = acc[c];
}

// ---------------------------------------------------------------------------
extern "C" void kernel_launch(void* const* d_in, const int* in_sizes, int n_in,
                              void* d_out, int out_size, void* d_ws, size_t ws_size,
                              hipStream_t stream) {
    const float* value   = (const float*)d_in[0];
    const float* key_map = (const float*)d_in[1];
    const float* state   = (const float*)d_in[2];
    const float* b_w     = (const float*)d_in[3];
    const float* a_w     = (const float*)d_in[4];
    const float* A_log   = (const float*)d_in[5];
    const float* dt_bias = (const float*)d_in[6];
    float* out = (float*)d_out;

    float* ws = (float*)d_ws;
    float* keyn  = ws;                       // B*K*HW f32      = 524288
    short* kbf   = (short*)(keyn + 524288);  // B*K*HW bf16     = 524288 shorts
    float* gram  = (float*)(kbf + 524288);   // B*K*K           =   8192
    float* part  = gram + 8192;              // B*N*K*C         = 524288
    float* beta8 = part + 524288;            // B*N*K*NH        =  16384
    float* nstat = beta8 + 16384;            // B*N*K*C         = 524288
    // total ~7.5 MB of d_ws

    k_softmax<<<BB * (HW / 64), 64, 0, stream>>>(key_map, keyn, kbf);
    k_gram<<<BB * KK * KK, 256, 0, stream>>>(keyn, gram);
    k_state<<<BB * NN * KK, 256, 0, stream>>>(state, gram, b_w, a_w, A_log, dt_bias,
                                              part, beta8);
    k_vkt_mfma<<<BB * NN * (CC / 32), 256, 0, stream>>>(kbf, value, part, beta8, nstat);
    k_readout<<<BB * NN * (CC / 16) * (HW / 256), 256, 0, stream>>>(keyn, nstat, out);
}

// Round 3
// 121.378 us; speedup vs baseline: 2.1110x; 1.3053x over previous
//
#include <hip/hip_runtime.h>
#include <hip/hip_bf16.h>

// Shapes (fixed for this problem)
#define BB 2
#define NN 16
#define CC 256
#define KK 64
#define HW 4096
#define NH 8

typedef __attribute__((ext_vector_type(4))) float f32x4;
typedef __attribute__((ext_vector_type(8))) short s16x8;

__device__ __forceinline__ short f2bf(float f) {
    __hip_bfloat16 h = __float2bfloat16(f);
    return *reinterpret_cast<short*>(&h);
}

// ---------------------------------------------------------------------------
// K1: key_n = softmax(key_map, axis=K). One thread per (b,hw); 64 values in regs.
// Emits: keyn f32 [b][k][hw] (for gram), kbf bf16 [b][k][hw] (vkt A-operand),
//        kbfT bf16 [b][hw][k] (readout B-operand, k-contiguous).
// ---------------------------------------------------------------------------
__global__ __launch_bounds__(64) void k_softmax(const float* __restrict__ km,
                                                float* __restrict__ keyn,
                                                short* __restrict__ kbf,
                                                short* __restrict__ kbfT) {
    const int b = blockIdx.x >> 6;                 // HW/64 = 64 blocks per b
    const int hw = (blockIdx.x & 63) * 64 + threadIdx.x;
    const float* p = km + (size_t)b * KK * HW + hw;
    float x[KK];
    float m = -1e30f;
#pragma unroll
    for (int k = 0; k < KK; k++) { x[k] = p[(size_t)k * HW]; m = fmaxf(m, x[k]); }
    float s = 0.f;
#pragma unroll
    for (int k = 0; k < KK; k++) { x[k] = __expf(x[k] - m); s += x[k]; }
    const float inv = 1.f / s;
    float* q = keyn + (size_t)b * KK * HW + hw;
    short* q2 = kbf + (size_t)b * KK * HW + hw;
#pragma unroll
    for (int k = 0; k < KK; k++) {
        x[k] *= inv;
        q[(size_t)k * HW] = x[k];
        q2[(size_t)k * HW] = f2bf(x[k]);
    }
    short* q3 = kbfT + ((size_t)b * HW + hw) * KK;
#pragma unroll
    for (int k8 = 0; k8 < KK; k8 += 8) {
        s16x8 v;
#pragma unroll
        for (int j = 0; j < 8; j++) v[j] = f2bf(x[k8 + j]);
        *(s16x8*)(q3 + k8) = v;
    }
}

// ---------------------------------------------------------------------------
// K2: gram[b,k,j] = sum_hw key_n[b,k,hw]*key_n[b,j,hw]. Block per (b,k,j).
// ---------------------------------------------------------------------------
__global__ __launch_bounds__(256) void k_gram(const float* __restrict__ keyn,
                                              float* __restrict__ gram) {
    const int tid = threadIdx.x;
    const int id = blockIdx.x;
    const int b = id >> 12;
    const int k = (id >> 6) & 63;
    const int j = id & 63;
    const float* pa = keyn + ((size_t)b * KK + k) * HW;
    const float* pb = keyn + ((size_t)b * KK + j) * HW;
    float s = 0.f;
    for (int i = tid; i < HW; i += 256) s = fmaf(pa[i], pb[i], s);
#pragma unroll
    for (int off = 32; off; off >>= 1) s += __shfl_down(s, off, 64);
    __shared__ float red[4];
    if ((tid & 63) == 0) red[tid >> 6] = s;
    __syncthreads();
    if (tid == 0) gram[id] = red[0] + red[1] + red[2] + red[3];
}

// ---------------------------------------------------------------------------
// K3: per (b,n,k): beta_h, alpha_h (dot over c), v_k (gram @ state),
//     part = alpha*(state - beta*v_k). Block per (b,n,k), thread = c.
// ---------------------------------------------------------------------------
__global__ __launch_bounds__(256) void k_state(const float* __restrict__ state,
                                               const float* __restrict__ gram,
                                               const float* __restrict__ b_w,
                                               const float* __restrict__ a_w,
                                               const float* __restrict__ A_log,
                                               const float* __restrict__ dt_bias,
                                               float* __restrict__ part,
                                               float* __restrict__ beta8) {
    const int tid = threadIdx.x;   // c
    const int id = blockIdx.x;     // (b*N+n)*K + k
    const int k = id & 63;
    const int bn = id >> 6;
    const int b = bn >> 4;
    const float* st = state + (size_t)bn * KK * CC;   // [j][c]
    const float s = st[(size_t)k * CC + tid];

    float pb[NH], pa[NH];
#pragma unroll
    for (int h = 0; h < NH; h++) {
        pb[h] = s * b_w[h * CC + tid];
        pa[h] = s * a_w[h * CC + tid];
    }
#pragma unroll
    for (int off = 32; off; off >>= 1) {
#pragma unroll
        for (int h = 0; h < NH; h++) {
            pb[h] += __shfl_down(pb[h], off, 64);
            pa[h] += __shfl_down(pa[h], off, 64);
        }
    }
    __shared__ float red[4][2 * NH];
    const int wave = tid >> 6, lane = tid & 63;
    if (lane == 0) {
#pragma unroll
        for (int h = 0; h < NH; h++) { red[wave][h] = pb[h]; red[wave][NH + h] = pa[h]; }
    }
    __syncthreads();
    const int h = tid >> 5;   // c / 32 (rep = 32)
    float braw = 0.f, araw = 0.f;
#pragma unroll
    for (int w = 0; w < 4; w++) { braw += red[w][h]; araw += red[w][NH + h]; }
    const float beta = 1.f / (1.f + __expf(-braw));
    const float xx = araw + dt_bias[h];
    const float sp = fmaxf(xx, 0.f) + log1pf(__expf(-fabsf(xx)));   // softplus
    const float alpha = -__expf(A_log[h]) * sp;

    const float* g = gram + ((size_t)b * KK + k) * KK;
    float vk = 0.f;
#pragma unroll
    for (int j = 0; j < KK; j++) vk = fmaf(g[j], st[(size_t)j * CC + tid], vk);

    part[(size_t)id * CC + tid] = alpha * (s - beta * vk);
    if ((tid & 31) == 0) beta8[(size_t)id * NH + h] = beta;
}

// ---------------------------------------------------------------------------
// K4 (MFMA): vk_t[b,n,k,c] = sum_hw key_n[b,k,hw] * value[b,n,c,hw]
//            ns = part + beta*vk_t, emitted as bf16 nsT[bn][c][k] (k-contig).
// Block per (b,n, 32-c tile): 256 blocks, 256 threads (4 waves, hw K-split).
// ---------------------------------------------------------------------------
__global__ __launch_bounds__(256) void k_vkt_mfma(const short* __restrict__ kbf,
                                                  const float* __restrict__ value,
                                                  const float* __restrict__ part,
                                                  const float* __restrict__ beta8,
                                                  short* __restrict__ nsT) {
    const int tid = threadIdx.x;
    const int id = blockIdx.x;        // bn*8 + ct
    const int ct = id & 7;
    const int bn = id >> 3;
    const int b  = bn >> 4;
    const int w = tid >> 6, lane = tid & 63;
    const int l15 = lane & 15;
    const int ko  = (lane >> 4) << 3;     // K offset within fragment: 0,8,16,24

    const short* Ap = kbf + (size_t)b * KK * HW + ko;                       // A: keyn[k][hw]
    const float* Vp = value + ((size_t)bn * CC + ct * 32) * HW + ko;        // B: value[c][hw]

    f32x4 acc[4][2];
#pragma unroll
    for (int m = 0; m < 4; m++)
#pragma unroll
        for (int n = 0; n < 2; n++) acc[m][n] = (f32x4){0.f, 0.f, 0.f, 0.f};

    const int hwbase = w * 1024;

    s16x8 a_cur[4];
    f32x4 v_cur[2][2];
#pragma unroll
    for (int m = 0; m < 4; m++)
        a_cur[m] = *(const s16x8*)(Ap + (size_t)(m * 16 + l15) * HW + hwbase);
#pragma unroll
    for (int n = 0; n < 2; n++) {
        const float* p = Vp + (size_t)(n * 16 + l15) * HW + hwbase;
        v_cur[n][0] = *(const f32x4*)p;
        v_cur[n][1] = *(const f32x4*)(p + 4);
    }

    for (int t = 0; t < 32; ++t) {
        s16x8 a_nxt[4];
        f32x4 v_nxt[2][2];
        if (t < 31) {                      // prefetch next K-chunk into regs
            const int h2 = hwbase + (t + 1) * 32;
#pragma unroll
            for (int m = 0; m < 4; m++)
                a_nxt[m] = *(const s16x8*)(Ap + (size_t)(m * 16 + l15) * HW + h2);
#pragma unroll
            for (int n = 0; n < 2; n++) {
                const float* p = Vp + (size_t)(n * 16 + l15) * HW + h2;
                v_nxt[n][0] = *(const f32x4*)p;
                v_nxt[n][1] = *(const f32x4*)(p + 4);
            }
        }
        s16x8 bf[2];
#pragma unroll
        for (int n = 0; n < 2; n++)
#pragma unroll
            for (int j = 0; j < 4; j++) {
                bf[n][j]     = f2bf(v_cur[n][0][j]);
                bf[n][4 + j] = f2bf(v_cur[n][1][j]);
            }
#pragma unroll
        for (int m = 0; m < 4; m++)
#pragma unroll
            for (int n = 0; n < 2; n++)
                acc[m][n] = __builtin_amdgcn_mfma_f32_16x16x32_bf16(a_cur[m], bf[n],
                                                                    acc[m][n], 0, 0, 0);
#pragma unroll
        for (int m = 0; m < 4; m++) a_cur[m] = a_nxt[m];
#pragma unroll
        for (int n = 0; n < 2; n++) { v_cur[n][0] = v_nxt[n][0]; v_cur[n][1] = v_nxt[n][1]; }
    }

    // cross-wave reduce (4 hw-quarters) + combine: ns = part + beta*vkt
    __shared__ float red[4][KK][33];
#pragma unroll
    for (int m = 0; m < 4; m++)
#pragma unroll
        for (int n = 0; n < 2; n++)
#pragma unroll
            for (int r = 0; r < 4; r++)
                red[w][m * 16 + (lane >> 4) * 4 + r][n * 16 + l15] = acc[m][n][r];

    __shared__ float betaL[KK];
    __shared__ float nsb[KK][33];
    if (tid < KK) betaL[tid] = beta8[(size_t)(bn * KK + tid) * NH + ct];   // head = ct
    __syncthreads();

    const int k  = tid >> 2;
    const int c8 = (tid & 3) * 8;
    const float bet = betaL[k];
    const size_t obase = ((size_t)bn * KK + k) * CC + ct * 32 + c8;
#pragma unroll
    for (int j = 0; j < 8; j++) {
        const int cl = c8 + j;
        const float s = red[0][k][cl] + red[1][k][cl] + red[2][k][cl] + red[3][k][cl];
        nsb[k][cl] = part[obase + j] + bet * s;
    }
    __syncthreads();

    // transposed bf16 store: nsT[bn][ct*32 + c][k], 16B per thread
    const int c  = tid >> 3;            // 0..31
    const int kq = (tid & 7) * 8;
    s16x8 v;
#pragma unroll
    for (int i = 0; i < 8; i++) v[i] = f2bf(nsb[kq + i][c]);
    *(s16x8*)(nsT + ((size_t)bn * CC + ct * 32 + c) * KK + kq) = v;
}

// ---------------------------------------------------------------------------
// K5 (MFMA): readout[b,n,c,hw] = sum_k key_n[b,k,hw] * ns[b,n,k,c]
// A = nsT[c][k] (m=c), B = kbfT[hw][k] (n=hw). Pure-register, no LDS/sync.
// Block = 4 waves; wave = 16-hw strip x 256 c; grid = 32 bn x 64 hw-tiles.
// ---------------------------------------------------------------------------
__global__ __launch_bounds__(256) void k_readout_mfma(const short* __restrict__ kbfT,
                                                      const short* __restrict__ nsT,
                                                      float* __restrict__ out) {
    const int tid = threadIdx.x;
    const int id = blockIdx.x;          // bn*64 + hwt
    const int hwt = id & 63;
    const int bn  = id >> 6;
    const int b   = bn >> 4;
    const int w = tid >> 6, lane = tid & 63;
    const int l15 = lane & 15, hi = lane >> 4;
    const int hw0 = hwt * 64 + w * 16;

    const short* Bp = kbfT + ((size_t)b * HW + hw0 + l15) * KK + hi * 8;
    const s16x8 b0 = *(const s16x8*)Bp;
    const s16x8 b1 = *(const s16x8*)(Bp + 32);

    const short* Ap = nsT + ((size_t)bn * CC + l15) * KK + hi * 8;
    float* op = out + ((size_t)bn * CC + hi * 4) * HW + hw0 + l15;

#pragma unroll
    for (int ct = 0; ct < 16; ct++) {
        const s16x8 a0 = *(const s16x8*)(Ap + (size_t)(ct * 16) * KK);
        const s16x8 a1 = *(const s16x8*)(Ap + (size_t)(ct * 16) * KK + 32);
        f32x4 acc = (f32x4){0.f, 0.f, 0.f, 0.f};
        acc = __builtin_amdgcn_mfma_f32_16x16x32_bf16(a0, b0, acc, 0, 0, 0);
        acc = __builtin_amdgcn_mfma_f32_16x16x32_bf16(a1, b1, acc, 0, 0, 0);
#pragma unroll
        for (int r = 0; r < 4; r++)
            op[(size_t)(ct * 16 + r) * HW] = acc[r];
    }
}

// ---------------------------------------------------------------------------
extern "C" void kernel_launch(void* const* d_in, const int* in_sizes, int n_in,
                              void* d_out, int out_size, void* d_ws, size_t ws_size,
                              hipStream_t stream) {
    const float* value   = (const float*)d_in[0];
    const float* key_map = (const float*)d_in[1];
    const float* state   = (const float*)d_in[2];
    const float* b_w     = (const float*)d_in[3];
    const float* a_w     = (const float*)d_in[4];
    const float* A_log   = (const float*)d_in[5];
    const float* dt_bias = (const float*)d_in[6];
    float* out = (float*)d_out;

    float* ws = (float*)d_ws;
    float* keyn  = ws;                        // B*K*HW f32       = 524288
    short* kbf   = (short*)(keyn + 524288);   // B*K*HW bf16      = 524288 sh
    short* kbfT  = kbf + 524288;              // B*HW*K bf16      = 524288 sh
    float* gram  = (float*)(kbfT + 524288);   // B*K*K            =   8192
    float* part  = gram + 8192;               // B*N*K*C          = 524288
    float* beta8 = part + 524288;             // B*N*K*NH         =  16384
    short* nsT   = (short*)(beta8 + 16384);   // B*N*C*K bf16     = 524288 sh
    // total ~7.2 MB of d_ws

    k_softmax<<<BB * (HW / 64), 64, 0, stream>>>(key_map, keyn, kbf, kbfT);
    k_gram<<<BB * KK * KK, 256, 0, stream>>>(keyn, gram);
    k_state<<<BB * NN * KK, 256, 0, stream>>>(state, gram, b_w, a_w, A_log, dt_bias,
                                              part, beta8);
    k_vkt_mfma<<<BB * NN * (CC / 32), 256, 0, stream>>>(kbf, value, part, beta8, nsT);
    k_readout_mfma<<<BB * NN * (HW / 64), 256, 0, stream>>>(kbfT, nsT, out);
}

// Round 4
// 120.014 us; speedup vs baseline: 2.1349x; 1.0114x over previous
//
#include <hip/hip_runtime.h>
#include <hip/hip_bf16.h>

// Shapes (fixed for this problem)
#define BB 2
#define NN 16
#define CC 256
#define KK 64
#define HW 4096
#define NH 8

typedef __attribute__((ext_vector_type(4))) float f32x4;
typedef __attribute__((ext_vector_type(8))) short s16x8;
typedef __attribute__((ext_vector_type(4))) short s16x4;

__device__ __forceinline__ short f2bf(float f) {
    __hip_bfloat16 h = __float2bfloat16(f);
    return *reinterpret_cast<short*>(&h);
}
__device__ __forceinline__ float bf2f(short s) {
    unsigned int u = ((unsigned int)(unsigned short)s) << 16;
    float f; __builtin_memcpy(&f, &u, 4); return f;
}

// ---------------------------------------------------------------------------
// K1: key_n = softmax(key_map, axis=K). One thread per (b,hw); 64 values in regs.
// Emits: kbf bf16 [b][k][hw] (vkt A / gram), kbfT bf16 [b][hw][k] (readout B).
// ---------------------------------------------------------------------------
__global__ __launch_bounds__(64) void k_softmax(const float* __restrict__ km,
                                                short* __restrict__ kbf,
                                                short* __restrict__ kbfT) {
    const int b = blockIdx.x >> 6;                 // HW/64 = 64 blocks per b
    const int hw = (blockIdx.x & 63) * 64 + threadIdx.x;
    const float* p = km + (size_t)b * KK * HW + hw;
    float x[KK];
    float m = -1e30f;
#pragma unroll
    for (int k = 0; k < KK; k++) { x[k] = p[(size_t)k * HW]; m = fmaxf(m, x[k]); }
    float s = 0.f;
#pragma unroll
    for (int k = 0; k < KK; k++) { x[k] = __expf(x[k] - m); s += x[k]; }
    const float inv = 1.f / s;
    short* q2 = kbf + (size_t)b * KK * HW + hw;
#pragma unroll
    for (int k = 0; k < KK; k++) {
        x[k] *= inv;
        q2[(size_t)k * HW] = f2bf(x[k]);
    }
    short* q3 = kbfT + ((size_t)b * HW + hw) * KK;
#pragma unroll
    for (int k8 = 0; k8 < KK; k8 += 8) {
        s16x8 v;
#pragma unroll
        for (int j = 0; j < 8; j++) v[j] = f2bf(x[k8 + j]);
        *(s16x8*)(q3 + k8) = v;
    }
}

// ---------------------------------------------------------------------------
// K2: gram[b,k,j] = sum_hw kn[b,k,hw]*kn[b,j,hw]. Symmetric: block per (b, k>=j),
// mirror store. bf16 input, f32 accumulate.
// ---------------------------------------------------------------------------
__global__ __launch_bounds__(256) void k_gram(const short* __restrict__ kbf,
                                              float* __restrict__ gram) {
    const int tid = threadIdx.x;
    const int id = blockIdx.x;              // b*2080 + t
    const int b = (id >= 2080) ? 1 : 0;
    const int t = id - b * 2080;
    int k = (int)((sqrtf(8.f * (float)t + 1.f) - 1.f) * 0.5f);
    while ((k + 1) * (k + 2) / 2 <= t) k++;
    while (k * (k + 1) / 2 > t) k--;
    const int j = t - k * (k + 1) / 2;

    const short* pa = kbf + ((size_t)b * KK + k) * HW + tid * 16;
    const short* pb = kbf + ((size_t)b * KK + j) * HW + tid * 16;
    const s16x8 a0 = *(const s16x8*)pa, a1 = *(const s16x8*)(pa + 8);
    const s16x8 b0 = *(const s16x8*)pb, b1 = *(const s16x8*)(pb + 8);
    float s = 0.f;
#pragma unroll
    for (int i = 0; i < 8; i++) {
        s = fmaf(bf2f(a0[i]), bf2f(b0[i]), s);
        s = fmaf(bf2f(a1[i]), bf2f(b1[i]), s);
    }
#pragma unroll
    for (int off = 32; off; off >>= 1) s += __shfl_down(s, off, 64);
    __shared__ float red[4];
    if ((tid & 63) == 0) red[tid >> 6] = s;
    __syncthreads();
    if (tid == 0) {
        const float tot = red[0] + red[1] + red[2] + red[3];
        gram[((size_t)b * KK + k) * KK + j] = tot;
        gram[((size_t)b * KK + j) * KK + k] = tot;
    }
}

// ---------------------------------------------------------------------------
// K3: gates only: beta/alpha per (b,n,k,h). Block per (b,n,k), thread = c.
// ---------------------------------------------------------------------------
__global__ __launch_bounds__(256) void k_gates(const float* __restrict__ state,
                                               const float* __restrict__ b_w,
                                               const float* __restrict__ a_w,
                                               const float* __restrict__ A_log,
                                               const float* __restrict__ dt_bias,
                                               float* __restrict__ betaH,
                                               float* __restrict__ alphaH) {
    const int tid = threadIdx.x;   // c
    const int id = blockIdx.x;     // (b*N+n)*K + k
    const int k = id & 63;
    const int bn = id >> 6;
    const float s = state[((size_t)bn * KK + k) * CC + tid];

    float pb[NH], pa[NH];
#pragma unroll
    for (int h = 0; h < NH; h++) {
        pb[h] = s * b_w[h * CC + tid];
        pa[h] = s * a_w[h * CC + tid];
    }
#pragma unroll
    for (int off = 32; off; off >>= 1) {
#pragma unroll
        for (int h = 0; h < NH; h++) {
            pb[h] += __shfl_down(pb[h], off, 64);
            pa[h] += __shfl_down(pa[h], off, 64);
        }
    }
    __shared__ float red[4][2 * NH];
    const int wave = tid >> 6, lane = tid & 63;
    if (lane == 0) {
#pragma unroll
        for (int h = 0; h < NH; h++) { red[wave][h] = pb[h]; red[wave][NH + h] = pa[h]; }
    }
    __syncthreads();
    if (tid < KK) {}   // keep all lanes for the reduce below
    const int h = tid >> 5;
    float braw = 0.f, araw = 0.f;
#pragma unroll
    for (int w = 0; w < 4; w++) { braw += red[w][h]; araw += red[w][NH + h]; }
    if ((tid & 31) == 0) {
        const float beta = 1.f / (1.f + __expf(-braw));
        const float xx = araw + dt_bias[h];
        const float sp = fmaxf(xx, 0.f) + log1pf(__expf(-fabsf(xx)));   // softplus
        const float alpha = -__expf(A_log[h]) * sp;
        betaH[(size_t)id * NH + h] = beta;
        alphaH[(size_t)id * NH + h] = alpha;
    }
}

// ---------------------------------------------------------------------------
// K4 (MFMA): vkt[k,c] = sum_hw kn[k,hw]*value[c,hw]; fused epilogue computes
// v_k = gram@state in-block and ns = alpha*(state - beta*v_k) + beta*vkt,
// stored bf16-transposed as nsT[bn][c][k].
// Block per (b,n, 16-c tile): 512 blocks (2/CU), 4 waves (hw K-split 4x1024),
// register pipeline depth 2.
// ---------------------------------------------------------------------------
__global__ __launch_bounds__(256, 2) void k_vkt_mfma(const short* __restrict__ kbf,
                                                     const float* __restrict__ value,
                                                     const float* __restrict__ gram,
                                                     const float* __restrict__ state,
                                                     const float* __restrict__ betaH,
                                                     const float* __restrict__ alphaH,
                                                     short* __restrict__ nsT) {
    const int tid = threadIdx.x;
    const int id = blockIdx.x;        // bn*16 + ct
    const int ct = id & 15;
    const int bn = id >> 4;
    const int b  = bn >> 4;
    const int head = ct >> 1;         // c-tile 16 -> one head (32 c per head)
    const int w = tid >> 6, lane = tid & 63;
    const int l15 = lane & 15, hi = lane >> 4;
    const int ko  = hi << 3;          // K offset within fragment: 0,8,16,24

    const short* Ap = kbf + (size_t)b * KK * HW + ko;                       // kn[k][hw]
    const float* Vp = value + ((size_t)bn * CC + ct * 16) * HW + ko;        // value[c][hw]

    f32x4 acc[4];
#pragma unroll
    for (int m = 0; m < 4; m++) acc[m] = (f32x4){0.f, 0.f, 0.f, 0.f};

    const int hwbase = w * 1024;

#define LOADA(dst, off)                                                        \
    {                                                                          \
        _Pragma("unroll") for (int m = 0; m < 4; m++)                          \
            dst[m] = *(const s16x8*)(Ap + (size_t)(m * 16 + l15) * HW + (off));\
    }
#define LOADV(dst, off)                                                        \
    {                                                                          \
        const float* p_ = Vp + (size_t)l15 * HW + (off);                       \
        dst[0] = *(const f32x4*)p_;                                            \
        dst[1] = *(const f32x4*)(p_ + 4);                                      \
    }

    s16x8 aA[4], aB[4];
    f32x4 vA[2], vB[2];
    LOADA(aA, hwbase); LOADV(vA, hwbase);
    LOADA(aB, hwbase + 32); LOADV(vB, hwbase + 32);

    for (int t = 0; t < 32; ++t) {
        s16x8 aN[4];
        f32x4 vN[2];
        if (t < 30) {
            const int h2 = hwbase + (t + 2) * 32;
            LOADA(aN, h2); LOADV(vN, h2);
        }
        s16x8 bfr;
#pragma unroll
        for (int j = 0; j < 4; j++) { bfr[j] = f2bf(vA[0][j]); bfr[4 + j] = f2bf(vA[1][j]); }
#pragma unroll
        for (int m = 0; m < 4; m++)
            acc[m] = __builtin_amdgcn_mfma_f32_16x16x32_bf16(aA[m], bfr, acc[m], 0, 0, 0);
#pragma unroll
        for (int m = 0; m < 4; m++) { aA[m] = aB[m]; aB[m] = aN[m]; }
#pragma unroll
        for (int n = 0; n < 2; n++) { vA[n] = vB[n]; vB[n] = vN[n]; }
    }
#undef LOADA
#undef LOADV

    // --- epilogue: cross-wave reduce + v_k + combine + transposed bf16 store
    __shared__ float red[4][KK][17];
#pragma unroll
    for (int m = 0; m < 4; m++)
#pragma unroll
        for (int r = 0; r < 4; r++)
            red[w][m * 16 + hi * 4 + r][l15] = acc[m][r];

    __shared__ float gramL[KK][65];
    __shared__ float stL[KK][16];
    __shared__ float alphaL[KK], betaL[KK];
    for (int i = tid; i < KK * KK; i += 256) gramL[i >> 6][i & 63] = gram[(size_t)b * KK * KK + i];
    for (int i = tid; i < KK * 16; i += 256)
        stL[i >> 4][i & 15] = state[(size_t)bn * KK * CC + (size_t)(i >> 4) * CC + ct * 16 + (i & 15)];
    if (tid < KK) {
        alphaL[tid] = alphaH[((size_t)bn * KK + tid) * NH + head];
        betaL[tid]  = betaH[((size_t)bn * KK + tid) * NH + head];
    }
    __syncthreads();

    const int k = tid >> 2, cq = (tid & 3) * 4;
    float vk[4] = {0.f, 0.f, 0.f, 0.f};
#pragma unroll 8
    for (int j = 0; j < KK; j++) {
        const float g = gramL[k][j];
        vk[0] = fmaf(g, stL[j][cq + 0], vk[0]);
        vk[1] = fmaf(g, stL[j][cq + 1], vk[1]);
        vk[2] = fmaf(g, stL[j][cq + 2], vk[2]);
        vk[3] = fmaf(g, stL[j][cq + 3], vk[3]);
    }
    __shared__ float nsb[KK][17];
    const float al = alphaL[k], be = betaL[k];
#pragma unroll
    for (int i = 0; i < 4; i++) {
        const int c = cq + i;
        const float vs = red[0][k][c] + red[1][k][c] + red[2][k][c] + red[3][k][c];
        nsb[k][c] = al * (stL[k][c] - be * vk[i]) + be * vs;
    }
    __syncthreads();

    const int c = tid >> 4, k4 = (tid & 15) * 4;
    s16x4 v;
#pragma unroll
    for (int i = 0; i < 4; i++) v[i] = f2bf(nsb[k4 + i][c]);
    *(s16x4*)(nsT + ((size_t)bn * CC + ct * 16 + c) * KK + k4) = v;
}

// ---------------------------------------------------------------------------
// K5 (MFMA): readout[b,n,c,hw] = sum_k kn[b,k,hw] * ns[b,n,k,c]
// A = nsT[c][k] (m=c), B = kbfT[hw][k] (n=hw). Pure-register, no LDS/sync.
// ---------------------------------------------------------------------------
__global__ __launch_bounds__(256) void k_readout_mfma(const short* __restrict__ kbfT,
                                                      const short* __restrict__ nsT,
                                                      float* __restrict__ out) {
    const int tid = threadIdx.x;
    const int id = blockIdx.x;          // bn*64 + hwt
    const int hwt = id & 63;
    const int bn  = id >> 6;
    const int b   = bn >> 4;
    const int w = tid >> 6, lane = tid & 63;
    const int l15 = lane & 15, hi = lane >> 4;
    const int hw0 = hwt * 64 + w * 16;

    const short* Bp = kbfT + ((size_t)b * HW + hw0 + l15) * KK + hi * 8;
    const s16x8 b0 = *(const s16x8*)Bp;
    const s16x8 b1 = *(const s16x8*)(Bp + 32);

    const short* Ap = nsT + ((size_t)bn * CC + l15) * KK + hi * 8;
    float* op = out + ((size_t)bn * CC + hi * 4) * HW + hw0 + l15;

#pragma unroll
    for (int ct = 0; ct < 16; ct++) {
        const s16x8 a0 = *(const s16x8*)(Ap + (size_t)(ct * 16) * KK);
        const s16x8 a1 = *(const s16x8*)(Ap + (size_t)(ct * 16) * KK + 32);
        f32x4 acc = (f32x4){0.f, 0.f, 0.f, 0.f};
        acc = __builtin_amdgcn_mfma_f32_16x16x32_bf16(a0, b0, acc, 0, 0, 0);
        acc = __builtin_amdgcn_mfma_f32_16x16x32_bf16(a1, b1, acc, 0, 0, 0);
#pragma unroll
        for (int r = 0; r < 4; r++)
            op[(size_t)(ct * 16 + r) * HW] = acc[r];
    }
}

// ---------------------------------------------------------------------------
extern "C" void kernel_launch(void* const* d_in, const int* in_sizes, int n_in,
                              void* d_out, int out_size, void* d_ws, size_t ws_size,
                              hipStream_t stream) {
    const float* value   = (const float*)d_in[0];
    const float* key_map = (const float*)d_in[1];
    const float* state   = (const float*)d_in[2];
    const float* b_w     = (const float*)d_in[3];
    const float* a_w     = (const float*)d_in[4];
    const float* A_log   = (const float*)d_in[5];
    const float* dt_bias = (const float*)d_in[6];
    float* out = (float*)d_out;

    short* kbf   = (short*)d_ws;              // B*K*HW bf16   = 524288 sh
    short* kbfT  = kbf + 524288;              // B*HW*K bf16   = 524288 sh
    float* gram  = (float*)(kbfT + 524288);   // B*K*K         =   8192 f32
    float* betaH = gram + 8192;               // B*N*K*NH      =  16384 f32
    float* alphaH= betaH + 16384;             // B*N*K*NH      =  16384 f32
    short* nsT   = (short*)(alphaH + 16384);  // B*N*C*K bf16  = 524288 sh
    // total ~3.3 MB of d_ws

    k_softmax<<<BB * (HW / 64), 64, 0, stream>>>(key_map, kbf, kbfT);
    k_gram<<<BB * (KK * (KK + 1) / 2), 256, 0, stream>>>(kbf, gram);
    k_gates<<<BB * NN * KK, 256, 0, stream>>>(state, b_w, a_w, A_log, dt_bias,
                                              betaH, alphaH);
    k_vkt_mfma<<<BB * NN * (CC / 16), 256, 0, stream>>>(kbf, value, gram, state,
                                                        betaH, alphaH, nsT);
    k_readout_mfma<<<BB * NN * (HW / 64), 256, 0, stream>>>(kbfT, nsT, out);
}

// Round 5
// 111.743 us; speedup vs baseline: 2.2930x; 1.0740x over previous
//
#include <hip/hip_runtime.h>
#include <hip/hip_bf16.h>

// Shapes (fixed for this problem)
#define BB 2
#define NN 16
#define CC 256
#define KK 64
#define HW 4096
#define NH 8

typedef __attribute__((ext_vector_type(4))) float f32x4;
typedef __attribute__((ext_vector_type(8))) short s16x8;
typedef __attribute__((ext_vector_type(4))) short s16x4;

__device__ __forceinline__ short f2bf(float f) {
    __hip_bfloat16 h = __float2bfloat16(f);
    return *reinterpret_cast<short*>(&h);
}
__device__ __forceinline__ float bf2f(short s) {
    unsigned int u = ((unsigned int)(unsigned short)s) << 16;
    float f; __builtin_memcpy(&f, &u, 4); return f;
}

// ---------------------------------------------------------------------------
// K1: key_n = softmax(key_map, axis=K). One thread per (b,hw); 64 values in regs.
// Emits: kbf bf16 [b][k][hw] (vkt A / gram), kbfT bf16 [b][hw][k] (readout B).
// ---------------------------------------------------------------------------
__global__ __launch_bounds__(64) void k_softmax(const float* __restrict__ km,
                                                short* __restrict__ kbf,
                                                short* __restrict__ kbfT) {
    const int b = blockIdx.x >> 6;                 // HW/64 = 64 blocks per b
    const int hw = (blockIdx.x & 63) * 64 + threadIdx.x;
    const float* p = km + (size_t)b * KK * HW + hw;
    float x[KK];
    float m = -1e30f;
#pragma unroll
    for (int k = 0; k < KK; k++) { x[k] = p[(size_t)k * HW]; m = fmaxf(m, x[k]); }
    float s = 0.f;
#pragma unroll
    for (int k = 0; k < KK; k++) { x[k] = __expf(x[k] - m); s += x[k]; }
    const float inv = 1.f / s;
    short* q2 = kbf + (size_t)b * KK * HW + hw;
#pragma unroll
    for (int k = 0; k < KK; k++) {
        x[k] *= inv;
        q2[(size_t)k * HW] = f2bf(x[k]);
    }
    short* q3 = kbfT + ((size_t)b * HW + hw) * KK;
#pragma unroll
    for (int k8 = 0; k8 < KK; k8 += 8) {
        s16x8 v;
#pragma unroll
        for (int j = 0; j < 8; j++) v[j] = f2bf(x[k8 + j]);
        *(s16x8*)(q3 + k8) = v;
    }
}

// ---------------------------------------------------------------------------
// K2: gram[b,k,j] = sum_hw kn[b,k,hw]*kn[b,j,hw]. Symmetric: block per (b, k>=j),
// mirror store. bf16 input, f32 accumulate.
// ---------------------------------------------------------------------------
__global__ __launch_bounds__(256) void k_gram(const short* __restrict__ kbf,
                                              float* __restrict__ gram) {
    const int tid = threadIdx.x;
    const int id = blockIdx.x;              // b*2080 + t
    const int b = (id >= 2080) ? 1 : 0;
    const int t = id - b * 2080;
    int k = (int)((sqrtf(8.f * (float)t + 1.f) - 1.f) * 0.5f);
    while ((k + 1) * (k + 2) / 2 <= t) k++;
    while (k * (k + 1) / 2 > t) k--;
    const int j = t - k * (k + 1) / 2;

    const short* pa = kbf + ((size_t)b * KK + k) * HW + tid * 16;
    const short* pb = kbf + ((size_t)b * KK + j) * HW + tid * 16;
    const s16x8 a0 = *(const s16x8*)pa, a1 = *(const s16x8*)(pa + 8);
    const s16x8 b0 = *(const s16x8*)pb, b1 = *(const s16x8*)(pb + 8);
    float s = 0.f;
#pragma unroll
    for (int i = 0; i < 8; i++) {
        s = fmaf(bf2f(a0[i]), bf2f(b0[i]), s);
        s = fmaf(bf2f(a1[i]), bf2f(b1[i]), s);
    }
#pragma unroll
    for (int off = 32; off; off >>= 1) s += __shfl_down(s, off, 64);
    __shared__ float red[4];
    if ((tid & 63) == 0) red[tid >> 6] = s;
    __syncthreads();
    if (tid == 0) {
        const float tot = red[0] + red[1] + red[2] + red[3];
        gram[((size_t)b * KK + k) * KK + j] = tot;
        gram[((size_t)b * KK + j) * KK + k] = tot;
    }
}

// ---------------------------------------------------------------------------
// K3: gates only: beta/alpha per (b,n,k,h). Block per (b,n,k), thread = c.
// ---------------------------------------------------------------------------
__global__ __launch_bounds__(256) void k_gates(const float* __restrict__ state,
                                               const float* __restrict__ b_w,
                                               const float* __restrict__ a_w,
                                               const float* __restrict__ A_log,
                                               const float* __restrict__ dt_bias,
                                               float* __restrict__ betaH,
                                               float* __restrict__ alphaH) {
    const int tid = threadIdx.x;   // c
    const int id = blockIdx.x;     // (b*N+n)*K + k
    const int k = id & 63;
    const int bn = id >> 6;
    const float s = state[((size_t)bn * KK + k) * CC + tid];

    float pb[NH], pa[NH];
#pragma unroll
    for (int h = 0; h < NH; h++) {
        pb[h] = s * b_w[h * CC + tid];
        pa[h] = s * a_w[h * CC + tid];
    }
#pragma unroll
    for (int off = 32; off; off >>= 1) {
#pragma unroll
        for (int h = 0; h < NH; h++) {
            pb[h] += __shfl_down(pb[h], off, 64);
            pa[h] += __shfl_down(pa[h], off, 64);
        }
    }
    __shared__ float red[4][2 * NH];
    const int wave = tid >> 6, lane = tid & 63;
    if (lane == 0) {
#pragma unroll
        for (int h = 0; h < NH; h++) { red[wave][h] = pb[h]; red[wave][NH + h] = pa[h]; }
    }
    __syncthreads();
    const int h = tid >> 5;
    float braw = 0.f, araw = 0.f;
#pragma unroll
    for (int w = 0; w < 4; w++) { braw += red[w][h]; araw += red[w][NH + h]; }
    if ((tid & 31) == 0) {
        const float beta = 1.f / (1.f + __expf(-braw));
        const float xx = araw + dt_bias[h];
        const float sp = fmaxf(xx, 0.f) + log1pf(__expf(-fabsf(xx)));   // softplus
        const float alpha = -__expf(A_log[h]) * sp;
        betaH[(size_t)id * NH + h] = beta;
        alphaH[(size_t)id * NH + h] = alpha;
    }
}

// ---------------------------------------------------------------------------
// K4 (MFMA): vkt[k,c] = sum_hw kn[k,hw]*value[c,hw]; fused epilogue computes
// v_k = gram@state in-block and ns = alpha*(state - beta*v_k) + beta*vkt,
// stored bf16-transposed as nsT[bn][c][k].
// Block per (b,n, 16-c tile): 512 blocks (2/CU), 4 waves.
// Pipeline: 16 chunks of 256 hw; value prefetched 3 chunks ahead into static
// register slots (vbuf[t%3], full unroll -> no rotation copies -> no spurious
// vmcnt waits); staged as bf16 in padded LDS; A-frags (L2) 1 iter ahead.
// Raw s_barrier + manual lgkmcnt keeps prefetch loads in flight across
// barriers (avoids the compiler's vmcnt(0) drain at __syncthreads).
// ---------------------------------------------------------------------------
__global__ __launch_bounds__(256) void k_vkt_mfma(const short* __restrict__ kbf,
                                                  const float* __restrict__ value,
                                                  const float* __restrict__ gram,
                                                  const float* __restrict__ state,
                                                  const float* __restrict__ betaH,
                                                  const float* __restrict__ alphaH,
                                                  short* __restrict__ nsT) {
    const int tid = threadIdx.x;
    const int id = blockIdx.x;        // bn*16 + ct
    const int ct = id & 15;
    const int bn = id >> 4;
    const int b  = bn >> 4;
    const int head = ct >> 1;         // 32 c per head, c-tile = 16
    const int w = tid >> 6, lane = tid & 63;
    const int l15 = lane & 15, hi = lane >> 4;
    const int ko  = hi << 3;          // K offset within fragment: 0,8,16,24

    __shared__ short Vs[2][16][264];  // bf16 V tile, padded (row stride 528 B)

    const short* Ap = kbf + (size_t)b * KK * HW + ko;                 // kn[k][hw]
    const int vrow = tid >> 4;                                        // 0..15 (c)
    const int vcol = (tid & 15) * 4;                                  // float idx
    const float* vsrc = value + ((size_t)bn * CC + ct * 16 + vrow) * HW + vcol;

    f32x4 vbuf[3][4];
    s16x8 abuf[2][2][4];
    f32x4 acc[4];
#pragma unroll
    for (int m = 0; m < 4; m++) acc[m] = (f32x4){0.f, 0.f, 0.f, 0.f};

#define VLOAD(slot, chunk)                                                     \
    {                                                                          \
        _Pragma("unroll") for (int j = 0; j < 4; j++)                          \
            vbuf[slot][j] = *(const f32x4*)(vsrc + (chunk) * 256 + j * 64);    \
    }
#define ALOAD(ab, titer)                                                       \
    {                                                                          \
        _Pragma("unroll") for (int s = 0; s < 2; s++)                          \
        _Pragma("unroll") for (int m = 0; m < 4; m++)                          \
            abuf[ab][s][m] = *(const s16x8*)(Ap + (size_t)(m * 16 + l15) * HW  \
                                             + (titer) * 256 + (w * 2 + s) * 32); \
    }
#define VCVT_STORE(slot, pbuf)                                                 \
    {                                                                          \
        _Pragma("unroll") for (int j = 0; j < 4; j++) {                        \
            s16x4 tmp;                                                         \
            _Pragma("unroll") for (int e = 0; e < 4; e++)                      \
                tmp[e] = f2bf(vbuf[slot][j][e]);                               \
            *(s16x4*)&Vs[pbuf][vrow][vcol + j * 64] = tmp;                     \
        }                                                                      \
    }

    // prologue: fill 3 V slots, A for iter 0, stage chunk 0 into Vs[0]
    VLOAD(0, 0); VLOAD(1, 1); VLOAD(2, 2);
    ALOAD(0, 0);
    VCVT_STORE(0, 0);
    asm volatile("s_waitcnt lgkmcnt(0)" ::: "memory");
    __builtin_amdgcn_s_barrier();

#pragma unroll
    for (int t = 0; t < 16; ++t) {
        if (t + 3 < 16) VLOAD(t % 3, t + 3);          // HBM prefetch, 3 ahead
        if (t + 1 < 16) ALOAD((t + 1) & 1, t + 1);    // L2 prefetch, 1 ahead
#pragma unroll
        for (int s = 0; s < 2; s++) {                 // wave's 2 k-steps
            const s16x8 bfrag =
                *(const s16x8*)&Vs[t & 1][l15][(w * 2 + s) * 32 + ko];
#pragma unroll
            for (int m = 0; m < 4; m++)
                acc[m] = __builtin_amdgcn_mfma_f32_16x16x32_bf16(
                    abuf[t & 1][s][m], bfrag, acc[m], 0, 0, 0);
        }
        if (t + 1 < 16) {
            VCVT_STORE((t + 1) % 3, (t + 1) & 1);     // stage next chunk
            asm volatile("s_waitcnt lgkmcnt(0)" ::: "memory");
            __builtin_amdgcn_s_barrier();
        }
    }
#undef VLOAD
#undef ALOAD
#undef VCVT_STORE

    // --- epilogue: cross-wave reduce + v_k + combine + transposed bf16 store
    __shared__ float red[4][KK][17];
#pragma unroll
    for (int m = 0; m < 4; m++)
#pragma unroll
        for (int r = 0; r < 4; r++)
            red[w][m * 16 + hi * 4 + r][l15] = acc[m][r];

    __shared__ float gramL[KK][65];
    __shared__ float stL[KK][16];
    __shared__ float alphaL[KK], betaL[KK];
    for (int i = tid; i < KK * KK; i += 256) gramL[i >> 6][i & 63] = gram[(size_t)b * KK * KK + i];
    for (int i = tid; i < KK * 16; i += 256)
        stL[i >> 4][i & 15] = state[(size_t)bn * KK * CC + (size_t)(i >> 4) * CC + ct * 16 + (i & 15)];
    if (tid < KK) {
        alphaL[tid] = alphaH[((size_t)bn * KK + tid) * NH + head];
        betaL[tid]  = betaH[((size_t)bn * KK + tid) * NH + head];
    }
    __syncthreads();

    const int k = tid >> 2, cq = (tid & 3) * 4;
    float vk[4] = {0.f, 0.f, 0.f, 0.f};
#pragma unroll 8
    for (int j = 0; j < KK; j++) {
        const float g = gramL[k][j];
        vk[0] = fmaf(g, stL[j][cq + 0], vk[0]);
        vk[1] = fmaf(g, stL[j][cq + 1], vk[1]);
        vk[2] = fmaf(g, stL[j][cq + 2], vk[2]);
        vk[3] = fmaf(g, stL[j][cq + 3], vk[3]);
    }
    __shared__ float nsb[KK][17];
    const float al = alphaL[k], be = betaL[k];
#pragma unroll
    for (int i = 0; i < 4; i++) {
        const int c = cq + i;
        const float vs = red[0][k][c] + red[1][k][c] + red[2][k][c] + red[3][k][c];
        nsb[k][c] = al * (stL[k][c] - be * vk[i]) + be * vs;
    }
    __syncthreads();

    const int c = tid >> 4, k4 = (tid & 15) * 4;
    s16x4 v;
#pragma unroll
    for (int i = 0; i < 4; i++) v[i] = f2bf(nsb[k4 + i][c]);
    *(s16x4*)(nsT + ((size_t)bn * CC + ct * 16 + c) * KK + k4) = v;
}

// ---------------------------------------------------------------------------
// K5 (MFMA): readout[b,n,c,hw] = sum_k kn[b,k,hw] * ns[b,n,k,c]
// A = nsT[c][k] (m=c), B = kbfT[hw][k] (n=hw). Pure-register, no LDS/sync.
// ---------------------------------------------------------------------------
__global__ __launch_bounds__(256) void k_readout_mfma(const short* __restrict__ kbfT,
                                                      const short* __restrict__ nsT,
                                                      float* __restrict__ out) {
    const int tid = threadIdx.x;
    const int id = blockIdx.x;          // bn*64 + hwt
    const int hwt = id & 63;
    const int bn  = id >> 6;
    const int b   = bn >> 6;
    const int w = tid >> 6, lane = tid & 63;
    const int l15 = lane & 15, hi = lane >> 4;
    const int hw0 = hwt * 64 + w * 16;

    const short* Bp = kbfT + ((size_t)(bn >> 4) * HW + hw0 + l15) * KK + hi * 8;
    const s16x8 b0 = *(const s16x8*)Bp;
    const s16x8 b1 = *(const s16x8*)(Bp + 32);

    const short* Ap = nsT + ((size_t)bn * CC + l15) * KK + hi * 8;
    float* op = out + ((size_t)bn * CC + hi * 4) * HW + hw0 + l15;

#pragma unroll
    for (int ct = 0; ct < 16; ct++) {
        const s16x8 a0 = *(const s16x8*)(Ap + (size_t)(ct * 16) * KK);
        const s16x8 a1 = *(const s16x8*)(Ap + (size_t)(ct * 16) * KK + 32);
        f32x4 acc = (f32x4){0.f, 0.f, 0.f, 0.f};
        acc = __builtin_amdgcn_mfma_f32_16x16x32_bf16(a0, b0, acc, 0, 0, 0);
        acc = __builtin_amdgcn_mfma_f32_16x16x32_bf16(a1, b1, acc, 0, 0, 0);
#pragma unroll
        for (int r = 0; r < 4; r++)
            op[(size_t)(ct * 16 + r) * HW] = acc[r];
    }
}

// ---------------------------------------------------------------------------
extern "C" void kernel_launch(void* const* d_in, const int* in_sizes, int n_in,
                              void* d_out, int out_size, void* d_ws, size_t ws_size,
                              hipStream_t stream) {
    const float* value   = (const float*)d_in[0];
    const float* key_map = (const float*)d_in[1];
    const float* state   = (const float*)d_in[2];
    const float* b_w     = (const float*)d_in[3];
    const float* a_w     = (const float*)d_in[4];
    const float* A_log   = (const float*)d_in[5];
    const float* dt_bias = (const float*)d_in[6];
    float* out = (float*)d_out;

    short* kbf   = (short*)d_ws;              // B*K*HW bf16   = 524288 sh
    short* kbfT  = kbf + 524288;              // B*HW*K bf16   = 524288 sh
    float* gram  = (float*)(kbfT + 524288);   // B*K*K         =   8192 f32
    float* betaH = gram + 8192;               // B*N*K*NH      =  16384 f32
    float* alphaH= betaH + 16384;             // B*N*K*NH      =  16384 f32
    short* nsT   = (short*)(alphaH + 16384);  // B*N*C*K bf16  = 524288 sh
    // total ~3.3 MB of d_ws

    k_softmax<<<BB * (HW / 64), 64, 0, stream>>>(key_map, kbf, kbfT);
    k_gram<<<BB * (KK * (KK + 1) / 2), 256, 0, stream>>>(kbf, gram);
    k_gates<<<BB * NN * KK, 256, 0, stream>>>(state, b_w, a_w, A_log, dt_bias,
                                              betaH, alphaH);
    k_vkt_mfma<<<BB * NN * (CC / 16), 256, 0, stream>>>(kbf, value, gram, state,
                                                        betaH, alphaH, nsT);
    k_readout_mfma<<<BB * NN * (HW / 64), 256, 0, stream>>>(kbfT, nsT, out);
}